// Round 5
// baseline (127.183 us; speedup 1.0000x reference)
//
#include <hip/hip_runtime.h>
#include <cstdint>
#include <cstddef>

// ---------------- workspace layout (bytes) ----------------
// act  : uint64[4][8][9][1024]   bit-packed activations, ((a*8+b)*9+c)*1024+l
// wbits: uint64[256][9]          weight sign bits (1 = +1)
// T    : int[512][9]             per-(b,ch) rect partial sums (b*576 + ch*9 + k)
// S1   : int[2304]               per-(o,c) exact integer sum of lin
// MUG  : float2[2304]            (mu, gamma/rsqrt(var+eps)) slow path only
// flag : int[256]                fast-path flag per output channel
static const size_t OFF_ACT  = 0;                  // 2359296 B
static const size_t OFF_W    = OFF_ACT + 2359296;  // 18432 B
static const size_t OFF_T    = OFF_W   + 18432;    // 18432 B
static const size_t OFF_S1   = OFF_T   + 18432;    // 9216 B
static const size_t OFF_MUG  = OFF_S1  + 9216;     // 18432 B
static const size_t OFF_FLAG = OFF_MUG + 18432;    // 1024 B

// integer sgn: exact for ints, folds to v_med3_i32
__device__ __forceinline__ int isgn(int e) {
  int t = e < -1 ? -1 : e;
  return t > 1 ? 1 : t;
}

// fused prep: [0,512) quant+rect partials; [512,800) act bit-pack; [800,864) wpack
__global__ __launch_bounds__(256) void k_prep(const float* __restrict__ x,
                                              const float* __restrict__ w,
                                              const float* __restrict__ gamma,
                                              const float* __restrict__ beta,
                                              int* __restrict__ T,
                                              uint64_t* __restrict__ act,
                                              uint64_t* __restrict__ wbits,
                                              int* __restrict__ flag) {
  int bid = blockIdx.x;
  int tid = threadIdx.x;
  if (bid < 512) {
    // ---- rect: quantize + 9 shifted-window popc partial sums per (b,ch) ----
    int base = bid << 10;
    int vals[9];
#pragma unroll
    for (int k = 0; k < 9; ++k) vals[k] = 0;
#pragma unroll
    for (int i = 0; i < 4; ++i) {
      int px = tid + i * 256;
      int h = px >> 5, ww = px & 31;
      float v = x[base + px];
      v = fminf(fmaxf(v, 0.f), 1.f);
      int q = (int)rintf(v * 15.f);
      int pc = __popc((unsigned)q);
      vals[0] += pc;
      if (h == 0) vals[1] += pc;
      if (h == 31) vals[2] += pc;
      if (ww == 0) vals[3] += pc;
      if (ww == 31) vals[4] += pc;
      if (h == 0 && ww == 0) vals[5] += pc;
      if (h == 0 && ww == 31) vals[6] += pc;
      if (h == 31 && ww == 0) vals[7] += pc;
      if (h == 31 && ww == 31) vals[8] += pc;
    }
#pragma unroll
    for (int k = 0; k < 9; ++k)
      for (int off = 32; off; off >>= 1) vals[k] += __shfl_down(vals[k], off, 64);
    __shared__ int red[4][9];
    int wid = tid >> 6, lane = tid & 63;
    if (lane == 0)
#pragma unroll
      for (int k = 0; k < 9; ++k) red[wid][k] = vals[k];
    __syncthreads();
    if (tid < 9) T[bid * 9 + tid] = red[0][tid] + red[1][tid] + red[2][tid] + red[3][tid];
  } else if (bid < 800) {
    // ---- apack: pack 4 bit-planes of 64 C9-channels per (b,c,l) ----
    int idx = (bid - 512) * 256 + tid;  // (b*9+c)*1024 + l, exact 73728
    int l = idx & 1023;
    int c = (idx >> 10) % 9;
    int b = idx / (9 * 1024);
    int h = l >> 5, w0 = l & 31;
    int i9 = c * 64;
    int ch = i9 / 9;
    int k = i9 - ch * 9;
    int ki = k / 3, kj = k - ki * 3;
    uint64_t b0 = 0, b1 = 0, b2 = 0, b3 = 0;
#pragma unroll 8
    for (int j = 0; j < 64; ++j) {
      int hh = h + ki - 1, ww = w0 + kj - 1;
      int q = 0;
      if ((unsigned)hh < 32u && (unsigned)ww < 32u) {
        float v = x[(((b * 64 + ch) << 10) + (hh << 5)) + ww];
        v = fminf(fmaxf(v, 0.f), 1.f);
        q = (int)rintf(v * 15.f);
      }
      b0 |= (uint64_t)(q & 1) << j;
      b1 |= (uint64_t)((q >> 1) & 1) << j;
      b2 |= (uint64_t)((q >> 2) & 1) << j;
      b3 |= (uint64_t)((q >> 3) & 1) << j;
      if (++kj == 3) { kj = 0; if (++ki == 3) { ki = 0; ++ch; } }
    }
    size_t stride = 8 * 9 * 1024;
    size_t off = ((size_t)b * 9 + c) * 1024 + l;
    act[0 * stride + off] = b0;
    act[1 * stride + off] = b1;
    act[2 * stride + off] = b2;
    act[3 * stride + off] = b3;
  } else {
    // ---- wpack: one wave per output channel (4 per block) ----
    int lane = tid & 63;
    int wid = tid >> 6;
    int o = (bid - 800) * 4 + wid;
    const float* row = w + (size_t)o * 576;
    double s = 0.0;
#pragma unroll
    for (int i = 0; i < 9; ++i) s += (double)row[lane + i * 64];
    for (int off = 32; off; off >>= 1) s += __shfl_down(s, off, 64);
    s = __shfl(s, 0, 64);
    float mean = (float)(s / 576.0);
#pragma unroll
    for (int c = 0; c < 9; ++c) {
      float v = row[c * 64 + lane];
      unsigned long long m = __ballot((v - mean) > 0.f);
      if (lane == 0) wbits[o * 9 + c] = (uint64_t)m;
    }
    if (lane == 0) flag[o] = (beta[o] == 0.f && gamma[o] > 0.f) ? 1 : 0;
  }
}

// T -> U -> S1 (one thread per (o,c) pair), + gated BN slow path
__global__ __launch_bounds__(256) void k_s1(const int* __restrict__ T,
                                            const uint64_t* __restrict__ wbits,
                                            const int* __restrict__ flag,
                                            const float* __restrict__ gamma,
                                            const uint64_t* __restrict__ act,
                                            int* __restrict__ S1,
                                            float2* __restrict__ MUG) {
  __shared__ int Tsh[576];
  __shared__ int Ush[9 * 65];  // padded: addr (c*65+j) -> 9 distinct banks
  int tid = threadIdx.x;
  for (int i = tid; i < 576; i += 256) {
    int acc = 0;
#pragma unroll
    for (int b = 0; b < 8; ++b) acc += T[b * 576 + i];
    Tsh[i] = acc;
  }
  __syncthreads();
  for (int i = tid; i < 576; i += 256) {
    int ch = i / 9;
    int k = i - ch * 9;
    int ki = k / 3, kj = k - ki * 3;
    const int* t = &Tsh[ch * 9];
    int u = t[0];
    if (ki == 0) u -= t[2]; else if (ki == 2) u -= t[1];
    if (kj == 0) u -= t[4]; else if (kj == 2) u -= t[3];
    if (ki == 0 && kj == 0) u += t[8];
    if (ki == 0 && kj == 2) u += t[7];
    if (ki == 2 && kj == 0) u += t[6];
    if (ki == 2 && kj == 2) u += t[5];
    Ush[(i >> 6) * 65 + (i & 63)] = u;  // index by chunk c = i/64, j = i%64
  }
  __syncthreads();
  int pair = blockIdx.x * 256 + tid;  // 9 blocks x 256 = 2304
  int o = pair / 9, c = pair - o * 9;
  uint64_t wv = wbits[pair];
  int tot = 0, pos = 0;
#pragma unroll 8
  for (int j = 0; j < 64; ++j) {
    int cnt = Ush[c * 65 + j];
    tot += cnt;
    if ((wv >> j) & 1) pos += cnt;
  }
  int s1 = 2 * pos - tot;
  S1[pair] = s1;
  // gated slow path (correctness-only; never taken with gamma>0, beta==0)
  if (!flag[o]) {
    int s2 = 0;
    for (int i = 0; i < 32768; ++i) {
      uint64_t av = act[((size_t)(i >> 10) * 9 + c) * 1024 + (i & 1023)];
      int lin = 2 * __popcll(av & wv) - __popcll(av);
      s2 += lin * lin;
    }
    float mu = (float)s1 * (1.f / 32768.f);
    float ex2 = (float)s2 * (1.f / 32768.f);
    float var = ex2 - mu * mu;
    if (var < 0.f) var = 0.f;
    MUG[pair] = make_float2(mu, gamma[o] / sqrtf(var + 1e-5f));
  }
}

// output v3: 4 output channels per wave, c-outer / a-inner.
// act traffic 4x lower (og=8 not 32); per-c weight rows are one-time scalar
// loads; hot loop is branch-free (wave-uniform allfast check hoisted).
__global__ __launch_bounds__(256, 8) void k_out(const uint64_t* __restrict__ act,
                                                const uint64_t* __restrict__ wbits,
                                                const int* __restrict__ S1,
                                                const float2* __restrict__ MUG,
                                                const int* __restrict__ flag,
                                                const float* __restrict__ beta,
                                                float* __restrict__ out) {
  int ltile = blockIdx.x;  // 0..7, 128 px per tile
  int og = blockIdx.y;     // 0..7
  int b = blockIdx.z;      // 0..7
  int tid = threadIdx.x;
  int lane = tid & 63;
  int wid = __builtin_amdgcn_readfirstlane(tid >> 6);  // 0..3 wave-uniform
  int op0 = og * 16 + wid * 4;  // 4 consecutive output channels
  int l = (ltile << 7) + lane * 2;

  int FL[2][4];
  int allfast = 1;
#pragma unroll
  for (int s = 0; s < 2; ++s)
#pragma unroll
    for (int oi = 0; oi < 4; ++oi) {
      FL[s][oi] = flag[s * 128 + op0 + oi];
      allfast &= FL[s][oi];
    }

  int M[2][4];  // [px][opi]
#pragma unroll
  for (int px = 0; px < 2; ++px)
#pragma unroll
    for (int oi = 0; oi < 4; ++oi) M[px][oi] = 0;

  if (allfast) {
    // ---- hot path: pure integer, no LDS, no per-unit branches ----
#pragma unroll 1
    for (int c = 0; c < 9; ++c) {
      uint64_t wv[2][4];
      int s1[2][4];
#pragma unroll
      for (int s = 0; s < 2; ++s)
#pragma unroll
        for (int oi = 0; oi < 4; ++oi) {
          int o = s * 128 + op0 + oi;
          wv[s][oi] = wbits[o * 9 + c];
          s1[s][oi] = S1[o * 9 + c];
        }
      const uint64_t* ap = act + ((size_t)b * 9 + c) * 1024 + l;
#pragma unroll
      for (int a = 0; a < 4; ++a) {
        uint64_t av0 = ap[(size_t)a * 73728];
        uint64_t av1 = ap[(size_t)a * 73728 + 1];
        int np0 = -((int)__popcll(av0) << 15);
        int np1 = -((int)__popcll(av1) << 15);
#pragma unroll
        for (int s = 0; s < 2; ++s)
#pragma unroll
          for (int oi = 0; oi < 4; ++oi) {
            uint64_t w = wv[s][oi];
            int t1 = s1[s][oi];
            int e0 = (((int)__popcll(av0 & w)) << 16) + np0 - t1;
            int e1 = (((int)__popcll(av1 & w)) << 16) + np1 - t1;
            M[0][oi] += isgn(e0) << (a + s);
            M[1][oi] += isgn(e1) << (a + s);
          }
      }
    }
#pragma unroll
    for (int oi = 0; oi < 4; ++oi) {
      size_t ob = ((size_t)b * 128 + op0 + oi) * 1024 + l;
      out[ob] = (float)M[0][oi] * (2.f / 45.f);
      out[ob + 1] = (float)M[1][oi] * (2.f / 45.f);
    }
  } else {
    // ---- general path (any flag combo); never taken with this data ----
    const float avec[4] = {1.f / 15.f, 2.f / 15.f, 4.f / 15.f, 8.f / 15.f};
    const float wvec[2] = {1.f / 3.f, 2.f / 3.f};
    float F[2][4];
#pragma unroll
    for (int px = 0; px < 2; ++px)
#pragma unroll
      for (int oi = 0; oi < 4; ++oi) F[px][oi] = 0.f;
    for (int c = 0; c < 9; ++c) {
      const uint64_t* ap = act + ((size_t)b * 9 + c) * 1024 + l;
      for (int a = 0; a < 4; ++a) {
        uint64_t av0 = ap[(size_t)a * 73728];
        uint64_t av1 = ap[(size_t)a * 73728 + 1];
        int pc0 = (int)__popcll(av0);
        int pc1 = (int)__popcll(av1);
        for (int s = 0; s < 2; ++s)
          for (int oi = 0; oi < 4; ++oi) {
            int o = s * 128 + op0 + oi;
            uint64_t w = wbits[o * 9 + c];
            if (FL[s][oi]) {
              int t1 = S1[o * 9 + c];
              int e0 = (((int)__popcll(av0 & w)) << 16) - (pc0 << 15) - t1;
              int e1 = (((int)__popcll(av1 & w)) << 16) - (pc1 << 15) - t1;
              M[0][oi] += isgn(e0) << (a + s);
              M[1][oi] += isgn(e1) << (a + s);
            } else {
              float2 m2 = MUG[o * 9 + c];
              float bb = beta[o];
              int l0 = 2 * (int)__popcll(av0 & w) - pc0;
              int l1 = 2 * (int)__popcll(av1 & w) - pc1;
              float bn0 = m2.y * ((float)l0 - m2.x) + bb;
              float bn1 = m2.y * ((float)l1 - m2.x) + bb;
              F[0][oi] += avec[a] * wvec[s] * ((bn0 > 0.f) ? 1.f : ((bn0 < 0.f) ? -1.f : 0.f));
              F[1][oi] += avec[a] * wvec[s] * ((bn1 > 0.f) ? 1.f : ((bn1 < 0.f) ? -1.f : 0.f));
            }
          }
      }
    }
#pragma unroll
    for (int oi = 0; oi < 4; ++oi) {
      size_t ob = ((size_t)b * 128 + op0 + oi) * 1024 + l;
      out[ob] = (float)M[0][oi] * (2.f / 45.f) + 2.f * F[0][oi];
      out[ob + 1] = (float)M[1][oi] * (2.f / 45.f) + 2.f * F[1][oi];
    }
  }
}

extern "C" void kernel_launch(void* const* d_in, const int* in_sizes, int n_in,
                              void* d_out, int out_size, void* d_ws, size_t ws_size,
                              hipStream_t stream) {
  const float* inputs = (const float*)d_in[0];
  const float* weight = (const float*)d_in[1];
  const float* gamma = (const float*)d_in[2];
  const float* beta = (const float*)d_in[3];
  float* out = (float*)d_out;

  char* ws = (char*)d_ws;
  uint64_t* act = (uint64_t*)(ws + OFF_ACT);
  uint64_t* wbits = (uint64_t*)(ws + OFF_W);
  int* T = (int*)(ws + OFF_T);
  int* S1 = (int*)(ws + OFF_S1);
  float2* MUG = (float2*)(ws + OFF_MUG);
  int* flag = (int*)(ws + OFF_FLAG);

  k_prep<<<864, 256, 0, stream>>>(inputs, weight, gamma, beta, T, act, wbits, flag);
  k_s1<<<9, 256, 0, stream>>>(T, wbits, flag, gamma, act, S1, MUG);
  k_out<<<dim3(8, 8, 8), 256, 0, stream>>>(act, wbits, S1, MUG, flag, beta, out);
}

// Round 6
// 102.397 us; speedup vs baseline: 1.2421x; 1.2421x over previous
//
#include <hip/hip_runtime.h>
#include <cstdint>
#include <cstddef>

// ---------------- workspace layout (bytes) ----------------
// act  : uint64[4][8][9][1024]   bit-packed activations, ((a*8+b)*9+c)*1024+l
// wbits: uint64[256][9]          weight sign bits (1 = +1)
// T    : int[512][9]             per-(b,ch) rect partial sums (b*576 + ch*9 + k)
// S1   : int[2304]               per-(o,c) exact integer sum of lin
// MUG  : float2[2304]            (mu, gamma/rsqrt(var+eps)) slow path only
// flag : int[256]                fast-path flag per output channel
static const size_t OFF_ACT  = 0;                  // 2359296 B
static const size_t OFF_W    = OFF_ACT + 2359296;  // 18432 B
static const size_t OFF_T    = OFF_W   + 18432;    // 18432 B
static const size_t OFF_S1   = OFF_T   + 18432;    // 9216 B
static const size_t OFF_MUG  = OFF_S1  + 9216;     // 18432 B
static const size_t OFF_FLAG = OFF_MUG + 18432;    // 1024 B

// integer sgn: exact for ints, folds to v_med3_i32
__device__ __forceinline__ int isgn(int e) {
  int t = e < -1 ? -1 : e;
  return t > 1 ? 1 : t;
}

// fused prep: [0,512) quant+rect; [512,1664) act bit-pack (4-way split); [1664,1728) wpack
__global__ __launch_bounds__(256) void k_prep(const float* __restrict__ x,
                                              const float* __restrict__ w,
                                              const float* __restrict__ gamma,
                                              const float* __restrict__ beta,
                                              int* __restrict__ T,
                                              uint64_t* __restrict__ act,
                                              uint64_t* __restrict__ wbits,
                                              int* __restrict__ flag) {
  int bid = blockIdx.x;
  int tid = threadIdx.x;
  if (bid < 512) {
    // ---- rect: quantize + 9 shifted-window popc partial sums per (b,ch) ----
    int base = bid << 10;
    int vals[9];
#pragma unroll
    for (int k = 0; k < 9; ++k) vals[k] = 0;
#pragma unroll
    for (int i = 0; i < 4; ++i) {
      int px = tid + i * 256;
      int h = px >> 5, ww = px & 31;
      float v = x[base + px];
      v = fminf(fmaxf(v, 0.f), 1.f);
      int q = (int)rintf(v * 15.f);
      int pc = __popc((unsigned)q);
      vals[0] += pc;
      if (h == 0) vals[1] += pc;
      if (h == 31) vals[2] += pc;
      if (ww == 0) vals[3] += pc;
      if (ww == 31) vals[4] += pc;
      if (h == 0 && ww == 0) vals[5] += pc;
      if (h == 0 && ww == 31) vals[6] += pc;
      if (h == 31 && ww == 0) vals[7] += pc;
      if (h == 31 && ww == 31) vals[8] += pc;
    }
#pragma unroll
    for (int k = 0; k < 9; ++k)
      for (int off = 32; off; off >>= 1) vals[k] += __shfl_down(vals[k], off, 64);
    __shared__ int red[4][9];
    int wid = tid >> 6, lane = tid & 63;
    if (lane == 0)
#pragma unroll
      for (int k = 0; k < 9; ++k) red[wid][k] = vals[k];
    __syncthreads();
    if (tid < 9) T[bid * 9 + tid] = red[0][tid] + red[1][tid] + red[2][tid] + red[3][tid];
  } else if (bid < 1664) {
    // ---- apack: 4-way split over j; each thread packs 16 bits of 4 planes ----
    int gidx = (bid - 512) * 256 + tid;       // 294912 threads
    int half = gidx & 3;                      // j-quarter: bits [half*16, half*16+16)
    int idx = gidx >> 2;                      // (b*9+c)*1024 + l
    int l = idx & 1023;
    int c = (idx >> 10) % 9;
    int b = idx / (9 * 1024);
    int h = l >> 5, w0 = l & 31;
    int i9 = c * 64 + half * 16;
    int ch = i9 / 9;
    int k = i9 - ch * 9;
    int ki = k / 3, kj = k - ki * 3;
    unsigned m0 = 0, m1 = 0, m2 = 0, m3 = 0;
#pragma unroll
    for (int jj = 0; jj < 16; ++jj) {
      int hh = h + ki - 1, ww = w0 + kj - 1;
      int q = 0;
      if ((unsigned)hh < 32u && (unsigned)ww < 32u) {
        float v = x[(((b * 64 + ch) << 10) + (hh << 5)) + ww];
        v = fminf(fmaxf(v, 0.f), 1.f);
        q = (int)rintf(v * 15.f);
      }
      m0 |= (unsigned)(q & 1) << jj;
      m1 |= (unsigned)((q >> 1) & 1) << jj;
      m2 |= (unsigned)((q >> 2) & 1) << jj;
      m3 |= (unsigned)((q >> 3) & 1) << jj;
      if (++kj == 3) { kj = 0; if (++ki == 3) { ki = 0; ++ch; } }
    }
    size_t stride = 8 * 9 * 1024;
    size_t off = ((size_t)b * 9 + c) * 1024 + l;
    unsigned short* a16 = (unsigned short*)act;
    a16[(0 * stride + off) * 4 + half] = (unsigned short)m0;
    a16[(1 * stride + off) * 4 + half] = (unsigned short)m1;
    a16[(2 * stride + off) * 4 + half] = (unsigned short)m2;
    a16[(3 * stride + off) * 4 + half] = (unsigned short)m3;
  } else {
    // ---- wpack: one wave per output channel (4 per block) ----
    int lane = tid & 63;
    int wid = tid >> 6;
    int o = (bid - 1664) * 4 + wid;
    const float* row = w + (size_t)o * 576;
    double s = 0.0;
#pragma unroll
    for (int i = 0; i < 9; ++i) s += (double)row[lane + i * 64];
    for (int off = 32; off; off >>= 1) s += __shfl_down(s, off, 64);
    s = __shfl(s, 0, 64);
    float mean = (float)(s / 576.0);
#pragma unroll
    for (int c = 0; c < 9; ++c) {
      float v = row[c * 64 + lane];
      unsigned long long m = __ballot((v - mean) > 0.f);
      if (lane == 0) wbits[o * 9 + c] = (uint64_t)m;
    }
    if (lane == 0) flag[o] = (beta[o] == 0.f && gamma[o] > 0.f) ? 1 : 0;
  }
}

// T -> U -> S1 (one thread per (o,c) pair), + gated BN slow path
__global__ __launch_bounds__(256) void k_s1(const int* __restrict__ T,
                                            const uint64_t* __restrict__ wbits,
                                            const int* __restrict__ flag,
                                            const float* __restrict__ gamma,
                                            const uint64_t* __restrict__ act,
                                            int* __restrict__ S1,
                                            float2* __restrict__ MUG) {
  __shared__ int Tsh[576];
  __shared__ int Ush[9 * 65];  // padded: addr (c*65+j) -> distinct banks
  int tid = threadIdx.x;
  for (int i = tid; i < 576; i += 256) {
    int acc = 0;
#pragma unroll
    for (int b = 0; b < 8; ++b) acc += T[b * 576 + i];
    Tsh[i] = acc;
  }
  __syncthreads();
  for (int i = tid; i < 576; i += 256) {
    int ch = i / 9;
    int k = i - ch * 9;
    int ki = k / 3, kj = k - ki * 3;
    const int* t = &Tsh[ch * 9];
    int u = t[0];
    if (ki == 0) u -= t[2]; else if (ki == 2) u -= t[1];
    if (kj == 0) u -= t[4]; else if (kj == 2) u -= t[3];
    if (ki == 0 && kj == 0) u += t[8];
    if (ki == 0 && kj == 2) u += t[7];
    if (ki == 2 && kj == 0) u += t[6];
    if (ki == 2 && kj == 2) u += t[5];
    Ush[(i >> 6) * 65 + (i & 63)] = u;  // chunk c = i/64, j = i%64
  }
  __syncthreads();
  int pair = blockIdx.x * 256 + tid;  // 9 blocks x 256 = 2304
  int o = pair / 9, c = pair - o * 9;
  uint64_t wv = wbits[pair];
  int tot = 0, pos = 0;
#pragma unroll 8
  for (int j = 0; j < 64; ++j) {
    int cnt = Ush[c * 65 + j];
    tot += cnt;
    if ((wv >> j) & 1) pos += cnt;
  }
  int s1 = 2 * pos - tot;
  S1[pair] = s1;
  // gated slow path (correctness-only; never taken with gamma>0, beta==0)
  if (!flag[o]) {
    int s2 = 0;
    for (int i = 0; i < 32768; ++i) {
      uint64_t av = act[((size_t)(i >> 10) * 9 + c) * 1024 + (i & 1023)];
      int lin = 2 * __popcll(av & wv) - __popcll(av);
      s2 += lin * lin;
    }
    float mu = (float)s1 * (1.f / 32768.f);
    float ex2 = (float)s2 * (1.f / 32768.f);
    float var = ex2 - mu * mu;
    if (var < 0.f) var = 0.f;
    MUG[pair] = make_float2(mu, gamma[o] / sqrtf(var + 1e-5f));
  }
}

// output (R4 structure): 2048 blocks, 2 output channels/wave, 2 px/lane,
// weights/S1 SGPR-hoisted once; wave-uniform allfast branch hoisted.
__global__ __launch_bounds__(256, 8) void k_out(const uint64_t* __restrict__ act,
                                                const uint64_t* __restrict__ wbits,
                                                const int* __restrict__ S1,
                                                const float2* __restrict__ MUG,
                                                const int* __restrict__ flag,
                                                const float* __restrict__ beta,
                                                float* __restrict__ out) {
  int ltile = blockIdx.x;  // 0..7, 128 px per tile
  int og = blockIdx.y;     // 0..31
  int b = blockIdx.z;      // 0..7
  int tid = threadIdx.x;
  int lane = tid & 63;
  int wid = __builtin_amdgcn_readfirstlane(tid >> 6);  // 0..3 wave-uniform
  int op = og * 4 + wid;  // output channel 0..127
  int l = (ltile << 7) + lane * 2;

  uint64_t Wv[2][9];
  int Sv[2][9];
  int FL[2];
#pragma unroll
  for (int s = 0; s < 2; ++s) {
    int o = s * 128 + op;
    FL[s] = flag[o];
#pragma unroll
    for (int c = 0; c < 9; ++c) {
      Wv[s][c] = wbits[o * 9 + c];
      Sv[s][c] = S1[o * 9 + c];
    }
  }

  int M0 = 0, M1 = 0;

  if (FL[0] & FL[1]) {
    // ---- hot path: pure integer, branch-free ----
    for (int a = 0; a < 4; ++a) {
      const uint64_t* ap = act + ((size_t)(a * 8 + b) * 9) * 1024 + l;
      int m00 = 0, m01 = 0, m10 = 0, m11 = 0;  // [s][px]
#pragma unroll
      for (int c = 0; c < 9; ++c) {
        uint64_t av0 = ap[c * 1024];      // adjacent pair -> dwordx4
        uint64_t av1 = ap[c * 1024 + 1];
        int np0 = -((int)__popcll(av0) << 15);
        int np1 = -((int)__popcll(av1) << 15);
        {
          uint64_t w = Wv[0][c];
          int t1 = Sv[0][c];
          m00 += isgn((((int)__popcll(av0 & w)) << 16) + np0 - t1);
          m01 += isgn((((int)__popcll(av1 & w)) << 16) + np1 - t1);
        }
        {
          uint64_t w = Wv[1][c];
          int t1 = Sv[1][c];
          m10 += isgn((((int)__popcll(av0 & w)) << 16) + np0 - t1);
          m11 += isgn((((int)__popcll(av1 & w)) << 16) + np1 - t1);
        }
      }
      M0 += (m00 + 2 * m10) << a;
      M1 += (m01 + 2 * m11) << a;
    }
    size_t ob = ((size_t)b * 128 + op) * 1024 + l;
    out[ob]     = (float)M0 * (2.f / 45.f);
    out[ob + 1] = (float)M1 * (2.f / 45.f);
  } else {
    // ---- general path (any flag combo); never taken with this data ----
    const float avec[4] = {1.f / 15.f, 2.f / 15.f, 4.f / 15.f, 8.f / 15.f};
    const float wvec[2] = {1.f / 3.f, 2.f / 3.f};
    float accf0 = 0.f, accf1 = 0.f;
    for (int a = 0; a < 4; ++a) {
      const uint64_t* ap = act + ((size_t)(a * 8 + b) * 9) * 1024 + l;
      int m00 = 0, m01 = 0, m10 = 0, m11 = 0;
      float f00 = 0.f, f01 = 0.f, f10 = 0.f, f11 = 0.f;
      for (int c = 0; c < 9; ++c) {
        uint64_t av0 = ap[c * 1024];
        uint64_t av1 = ap[c * 1024 + 1];
        int np0 = -((int)__popcll(av0) << 15);
        int np1 = -((int)__popcll(av1) << 15);
        for (int s = 0; s < 2; ++s) {
          uint64_t w = Wv[s][c];
          if (FL[s]) {
            int t1 = Sv[s][c];
            int e0 = (((int)__popcll(av0 & w)) << 16) + np0 - t1;
            int e1 = (((int)__popcll(av1 & w)) << 16) + np1 - t1;
            int g0 = isgn(e0), g1 = isgn(e1);
            if (s == 0) { m00 += g0; m01 += g1; } else { m10 += g0; m11 += g1; }
          } else {
            int o = s * 128 + op;
            float2 m2 = MUG[o * 9 + c];
            float bb = beta[o];
            int l0 = 2 * (int)__popcll(av0 & w) + (np0 >> 15);
            int l1 = 2 * (int)__popcll(av1 & w) + (np1 >> 15);
            float bn0 = m2.y * ((float)l0 - m2.x) + bb;
            float bn1 = m2.y * ((float)l1 - m2.x) + bb;
            float g0 = (bn0 > 0.f) ? 1.f : ((bn0 < 0.f) ? -1.f : 0.f);
            float g1 = (bn1 > 0.f) ? 1.f : ((bn1 < 0.f) ? -1.f : 0.f);
            if (s == 0) { f00 += g0; f01 += g1; } else { f10 += g0; f11 += g1; }
          }
        }
      }
      M0 += (m00 + 2 * m10) << a;
      M1 += (m01 + 2 * m11) << a;
      accf0 += avec[a] * (wvec[0] * f00 + wvec[1] * f10);
      accf1 += avec[a] * (wvec[0] * f01 + wvec[1] * f11);
    }
    size_t ob = ((size_t)b * 128 + op) * 1024 + l;
    out[ob]     = (float)M0 * (2.f / 45.f) + 2.f * accf0;
    out[ob + 1] = (float)M1 * (2.f / 45.f) + 2.f * accf1;
  }
}

extern "C" void kernel_launch(void* const* d_in, const int* in_sizes, int n_in,
                              void* d_out, int out_size, void* d_ws, size_t ws_size,
                              hipStream_t stream) {
  const float* inputs = (const float*)d_in[0];
  const float* weight = (const float*)d_in[1];
  const float* gamma = (const float*)d_in[2];
  const float* beta = (const float*)d_in[3];
  float* out = (float*)d_out;

  char* ws = (char*)d_ws;
  uint64_t* act = (uint64_t*)(ws + OFF_ACT);
  uint64_t* wbits = (uint64_t*)(ws + OFF_W);
  int* T = (int*)(ws + OFF_T);
  int* S1 = (int*)(ws + OFF_S1);
  float2* MUG = (float2*)(ws + OFF_MUG);
  int* flag = (int*)(ws + OFF_FLAG);

  k_prep<<<1728, 256, 0, stream>>>(inputs, weight, gamma, beta, T, act, wbits, flag);
  k_s1<<<9, 256, 0, stream>>>(T, wbits, flag, gamma, act, S1, MUG);
  k_out<<<dim3(8, 32, 8), 256, 0, stream>>>(act, wbits, S1, MUG, flag, beta, out);
}